// Round 8
// baseline (194.108 us; speedup 1.0000x reference)
//
#include <hip/hip_runtime.h>
#include <hip/hip_bf16.h>
#include <math.h>

// B=8, Cin=Cout=128, H=W=64, K=3, S=1, P=1
// All-f16 pipeline (f16 MFMA rate == bf16; more mantissa than bf16).
// ws layout (total 8,757,248 B < proven-safe 10,747,904 B):
//   wT    f16 [9][128 co][128 c]  @ 0        (294,912 B)
//   woffT f16 [9][32 oc][128 c]   @ 294,912  ( 73,728 B)  oc>=18 zero
//   xT    f16 [8][64][64][128]    @ 368,640  (8,388,608 B)

typedef _Float16 f16x8 __attribute__((ext_vector_type(8)));
typedef _Float16 h2    __attribute__((ext_vector_type(2)));
typedef float    f32x4 __attribute__((ext_vector_type(4)));

union U4 { uint4 u; h2 h[4]; f16x8 v; };

// ------------------------------------------------------------------
// Kernel P: repack w / w_offset into MFMA-fragment-ready f16.
// ------------------------------------------------------------------
__global__ __launch_bounds__(256) void prep_weights(
    const float* __restrict__ w, const float* __restrict__ woff,
    _Float16* __restrict__ wT, _Float16* __restrict__ woffT) {
    int idx = blockIdx.x * 256 + threadIdx.x;
    if (idx < 147456) {
        int c  = idx & 127;
        int co = (idx >> 7) & 127;
        int kk = idx >> 14;
        wT[idx] = (_Float16)w[co * 1152 + c * 9 + kk];
    }
    if (idx < 36864) {
        int c  = idx & 127;
        int oc = (idx >> 7) & 31;
        int kk = idx >> 12;
        woffT[idx] = (oc < 18) ? (_Float16)woff[oc * 1152 + c * 9 + kk] : (_Float16)0.f;
    }
}

// ------------------------------------------------------------------
// Kernel A: NCHW fp32 -> NHWC f16 (pair-packed uint writes).
// ------------------------------------------------------------------
__global__ __launch_bounds__(256) void transpose_nchw_nhwc(
    const float* __restrict__ x, unsigned* __restrict__ xT) {
    __shared__ float tile[128][65];
    int bh = blockIdx.x;                 // b*64 + h
    int b = bh >> 6, h = bh & 63;
    const float* src = x + b * 524288 + h * 64;
    for (int idx = threadIdx.x; idx < 8192; idx += 256) {
        int c = idx >> 6, ww = idx & 63;
        tile[c][ww] = src[c * 4096 + ww];
    }
    __syncthreads();
    unsigned* dst = xT + (size_t)bh * 4096;   // [w][c/2] as uint
    for (int idx = threadIdx.x; idx < 4096; idx += 256) {
        int ww = idx >> 6, c2 = (idx & 63) * 2;
        union { h2 h; unsigned u; } p;
        p.h = h2{(_Float16)tile[c2][ww], (_Float16)tile[c2 + 1][ww]};
        dst[idx] = p.u;
    }
}

// ------------------------------------------------------------------
// Kernel C: fused deformable conv, barrier-free main loop.
// Block = (b,ho) row, 256 thr (4 waves); XCD swizzle b = blockIdx&7.
// Phase A (coop): offset conv MFMA -> s_off.  Phase B (coop): meta.
// Main (wave-private, NO barriers): wave w owns pos [w*16, w*16+16);
// lane samples its MFMA A-fragment elements directly (pos = l&15,
// c = ks*32 + (l>>4)*8 + j) with packed-f16 blends; B-frags from wT;
// 32 MFMA per kk; acc covers all 128 cout for the wave's 16 pos.
// ------------------------------------------------------------------
__global__ __launch_bounds__(256, 2) void deform_fused(
    const _Float16* __restrict__ xT,
    const _Float16* __restrict__ wT,
    const _Float16* __restrict__ woffT,
    float* __restrict__ out) {
    __shared__ float  s_off[18][64];            // [oc][pos] offsets
    __shared__ int4   s_pix[576];               // [kk][pos] corner byte offsets
    __shared__ float4 s_wt[576];                // [kk][pos] mask-folded weights

    int raw = blockIdx.x;
    int b  = raw & 7;                    // XCD-locality: batch == XCD
    int ho = raw >> 3;
    int t = threadIdx.x, l = t & 63, w = t >> 6;   // w = wave 0..3
    int lr = l & 15, lg = l >> 4;
    const char* xb = (const char*)xT + (size_t)b * 1048576;

    // ---- Phase A: offset conv (M=64 pos, N=32 pad, K=1152). Wave w = pos tile. ----
    {
        f32x4 oacc0 = {0.f,0.f,0.f,0.f}, oacc1 = {0.f,0.f,0.f,0.f};
        for (int kk = 0; kk < 9; ++kk) {
            int y = ho + kk / 3 - 1;
            if ((unsigned)y >= 64u) continue;          // zero A row: skip
            int xcol = w * 16 + lr + kk % 3 - 1;
            bool vx = (unsigned)xcol < 64u;
            const _Float16* wo = woffT + (kk * 32 + lr) * 128 + lg * 8;
#pragma unroll
            for (int kg = 0; kg < 4; ++kg) {
                f16x8 A = {};
                if (vx) A = *(const f16x8*)(xb + ((y * 64 + xcol) * 128 + kg * 32 + lg * 8) * 2);
                oacc0 = __builtin_amdgcn_mfma_f32_16x16x32_f16(A, *(const f16x8*)(wo + kg * 32),        oacc0, 0, 0, 0);
                oacc1 = __builtin_amdgcn_mfma_f32_16x16x32_f16(A, *(const f16x8*)(wo + 2048 + kg * 32), oacc1, 0, 0, 0);
            }
        }
        // D: row = pos-in-16 = lg*4+r, col = oc-in-16 = lr
#pragma unroll
        for (int r = 0; r < 4; ++r)
            s_off[lr][w * 16 + lg * 4 + r] = oacc0[r];      // oc = lr < 18 always
        if (lr < 2) {
#pragma unroll
            for (int r = 0; r < 4; ++r)
                s_off[16 + lr][w * 16 + lg * 4 + r] = oacc1[r];
        }
    }
    __syncthreads();

    // ---- Phase B: bilinear meta for all (kk, pos) ----
    for (int e = t; e < 576; e += 256) {
        int pos = e & 63, kk = e >> 6;
        float dy = s_off[2 * kk][pos], dx = s_off[2 * kk + 1][pos];
        float py = (float)(ho + kk / 3 - 1) + dy;
        float px = (float)(pos + kk % 3 - 1) + dx;
        float y0f = floorf(py), x0f = floorf(px);
        float ly = py - y0f, lx = px - x0f;
        int y0 = (int)y0f, x0 = (int)x0f;
        int y1 = y0 + 1, x1 = x0 + 1;
        float my0 = ((unsigned)y0 < 64u) ? 1.f : 0.f;
        float my1 = ((unsigned)y1 < 64u) ? 1.f : 0.f;
        float mx0 = ((unsigned)x0 < 64u) ? 1.f : 0.f;
        float mx1 = ((unsigned)x1 < 64u) ? 1.f : 0.f;
        int y0c = min(max(y0, 0), 63), y1c = min(max(y1, 0), 63);
        int x0c = min(max(x0, 0), 63), x1c = min(max(x1, 0), 63);
        s_pix[e] = make_int4((y0c * 64 + x0c) * 256, (y0c * 64 + x1c) * 256,
                             (y1c * 64 + x0c) * 256, (y1c * 64 + x1c) * 256);
        s_wt[e] = make_float4((1.f - ly) * (1.f - lx) * my0 * mx0,
                              (1.f - ly) * lx * my0 * mx1,
                              ly * (1.f - lx) * my1 * mx0,
                              ly * lx * my1 * mx1);
    }
    __syncthreads();

    // ---- Main loop: wave-private, barrier-free ----
    int wb = w * 16;                       // wave's pos base
    f32x4 acc[8] = {{0.f,0.f,0.f,0.f},{0.f,0.f,0.f,0.f},{0.f,0.f,0.f,0.f},{0.f,0.f,0.f,0.f},
                    {0.f,0.f,0.f,0.f},{0.f,0.f,0.f,0.f},{0.f,0.f,0.f,0.f},{0.f,0.f,0.f,0.f}};

    for (int kk = 0; kk < 9; ++kk) {
        int e = kk * 64 + wb + lr;
        int4 pix = s_pix[e];
        float4 wt = s_wt[e];
        _Float16 wx = (_Float16)wt.x, wy = (_Float16)wt.y,
                 wz = (_Float16)wt.z, ww2 = (_Float16)wt.w;
        h2 w0 = h2{wx, wx}, w1 = h2{wy, wy}, w2 = h2{wz, wz}, w3 = h2{ww2, ww2};

        // A-frags: sample directly into fragment layout (pos = lr, c = ks*32+lg*8+j)
        f16x8 a[4];
#pragma unroll
        for (int ks = 0; ks < 4; ++ks) {
            int c2 = (ks * 32 + lg * 8) * 2;
            U4 v00, v01, v10, v11, s;
            v00.u = *(const uint4*)(xb + pix.x + c2);
            v01.u = *(const uint4*)(xb + pix.y + c2);
            v10.u = *(const uint4*)(xb + pix.z + c2);
            v11.u = *(const uint4*)(xb + pix.w + c2);
#pragma unroll
            for (int j = 0; j < 4; ++j)
                s.h[j] = w0 * v00.h[j] + w1 * v01.h[j] + w2 * v10.h[j] + w3 * v11.h[j];
            a[ks] = s.v;
        }
        // B-frags from wT + 32 MFMAs (8 independent acc chains)
        const _Float16* wkk = wT + (kk * 128 + lr) * 128 + lg * 8;
#pragma unroll
        for (int ks = 0; ks < 4; ++ks) {
#pragma unroll
            for (int cot = 0; cot < 8; ++cot) {
                f16x8 Bf = *(const f16x8*)(wkk + cot * 2048 + ks * 32);
                acc[cot] = __builtin_amdgcn_mfma_f32_16x16x32_f16(a[ks], Bf, acc[cot], 0, 0, 0);
            }
        }
    }

    // Epilogue: D row = pos-in-16 = lg*4+r, col = cout-in-16 = lr.
    // Lane holds 4 consecutive wo per cot -> float4 stores.
    float* ob = out + ((size_t)(b * 128 + lr)) * 4096 + ho * 64 + wb + lg * 4;
#pragma unroll
    for (int cot = 0; cot < 8; ++cot)
        *(float4*)(ob + (size_t)cot * 16 * 4096) =
            make_float4(acc[cot][0], acc[cot][1], acc[cot][2], acc[cot][3]);
}

// ------------------------------------------------------------------
extern "C" void kernel_launch(void* const* d_in, const int* in_sizes, int n_in,
                              void* d_out, int out_size, void* d_ws, size_t ws_size,
                              hipStream_t stream) {
    const float* x    = (const float*)d_in[0];
    const float* woff = (const float*)d_in[1];
    const float* w    = (const float*)d_in[2];
    float* out = (float*)d_out;

    _Float16* wT    = (_Float16*)d_ws;                     // 294,912 B
    _Float16* woffT = (_Float16*)((char*)d_ws + 294912);   //  73,728 B
    _Float16* xT    = (_Float16*)((char*)d_ws + 368640);   // 8,388,608 B

    prep_weights<<<576, 256, 0, stream>>>(w, woff, wT, woffT);
    transpose_nchw_nhwc<<<512, 256, 0, stream>>>(x, (unsigned*)xT);
    deform_fused<<<512, 256, 0, stream>>>(xT, wT, woffT, out);
}

// Round 10
// 144.509 us; speedup vs baseline: 1.3432x; 1.3432x over previous
//
#include <hip/hip_runtime.h>
#include <hip/hip_bf16.h>
#include <math.h>

// B=8, Cin=Cout=128, H=W=64, K=3, S=1, P=1
// All-f16 pipeline. ws layout (total 8,757,248 B < proven-safe 10,747,904 B):
//   wT    f16 [9][128 co][128 c]  @ 0        (294,912 B)
//   woffT f16 [9][32 oc][128 c]   @ 294,912  ( 73,728 B)  oc>=18 zero
//   xT    f16 [8][64][64][128]    @ 368,640  (8,388,608 B)

typedef _Float16 f16x8 __attribute__((ext_vector_type(8)));
typedef _Float16 h2    __attribute__((ext_vector_type(2)));
typedef float    f32x4 __attribute__((ext_vector_type(4)));

// ------------------------------------------------------------------
// Kernel P: repack w / w_offset into MFMA-fragment-ready f16.
// ------------------------------------------------------------------
__global__ __launch_bounds__(256) void prep_weights(
    const float* __restrict__ w, const float* __restrict__ woff,
    _Float16* __restrict__ wT, _Float16* __restrict__ woffT) {
    int idx = blockIdx.x * 256 + threadIdx.x;
    if (idx < 147456) {
        int c  = idx & 127;
        int co = (idx >> 7) & 127;
        int kk = idx >> 14;
        wT[idx] = (_Float16)w[co * 1152 + c * 9 + kk];
    }
    if (idx < 36864) {
        int c  = idx & 127;
        int oc = (idx >> 7) & 31;
        int kk = idx >> 12;
        woffT[idx] = (oc < 18) ? (_Float16)woff[oc * 1152 + c * 9 + kk] : (_Float16)0.f;
    }
}

// ------------------------------------------------------------------
// Kernel A: NCHW fp32 -> NHWC f16 (pair-packed uint writes).
// ------------------------------------------------------------------
__global__ __launch_bounds__(256) void transpose_nchw_nhwc(
    const float* __restrict__ x, unsigned* __restrict__ xT) {
    __shared__ float tile[128][65];
    int bh = blockIdx.x;                 // b*64 + h
    int b = bh >> 6, h = bh & 63;
    const float* src = x + b * 524288 + h * 64;
    for (int idx = threadIdx.x; idx < 8192; idx += 256) {
        int c = idx >> 6, ww = idx & 63;
        tile[c][ww] = src[c * 4096 + ww];
    }
    __syncthreads();
    unsigned* dst = xT + (size_t)bh * 4096;   // [w][c/2] as uint
    for (int idx = threadIdx.x; idx < 4096; idx += 256) {
        int ww = idx >> 6, c2 = (idx & 63) * 2;
        union { h2 h; unsigned u; } p;
        p.h = h2{(_Float16)tile[c2][ww], (_Float16)tile[c2 + 1][ww]};
        dst[idx] = p.u;
    }
}

// ------------------------------------------------------------------
// Kernel C: fused deformable conv. Block = (b,ho) row, 512 thr (8 waves).
// XCD swizzle: b = blockIdx&7.
// Phase A: offset conv MFMA -> s_off, with A(kk+1) prefetch rotation.
// Phase B: bilinear meta.
// Main: per kk — issue W(kk+1)+gathers(kk+1); MFMA(kk) reads W from regs
// (prefetched last iter) + S from LDS tile => NO vmcnt before MFMA; the
// only vmcnt(0) is at blend(kk+1), after the MFMA cluster. 1 barrier/kk.
// ------------------------------------------------------------------
__global__ __launch_bounds__(512, 4) void deform_fused(
    const _Float16* __restrict__ xT,
    const _Float16* __restrict__ wT,
    const _Float16* __restrict__ woffT,
    float* __restrict__ out) {
    __shared__ unsigned short s_tile[2][8192];  // dbuf [64 pos][128 c], XOR-16B swizzle
    __shared__ float  s_off[18][64];            // [oc][pos]
    __shared__ int4   s_pix[576];               // [kk][pos] corner byte offsets
    __shared__ float4 s_wt[576];                // [kk][pos] mask-folded weights

    int raw = blockIdx.x;
    int b  = raw & 7;                    // XCD-locality: batch == XCD
    int ho = raw >> 3;
    int t = threadIdx.x, l = t & 63, w = t >> 6;
    int lr = l & 15, lg = l >> 4;
    const char* xb = (const char*)xT + (size_t)b * 1048576;

    // ---- Phase A: offset conv (M=64, N=32, K=1152), prefetch rotation ----
    {
        int m4 = w >> 1, n2 = w & 1;
        f16x8 A[2][4];
        f32x4 oacc = {0.f, 0.f, 0.f, 0.f};
        auto loadA = [&](int kk, f16x8* dst) {
            int y = ho + kk / 3 - 1;
            int xcol = m4 * 16 + lr + kk % 3 - 1;
            bool valid = ((unsigned)y < 64u) && ((unsigned)xcol < 64u);
            int yc = min(max(y, 0), 63), xc = min(max(xcol, 0), 63);
            const char* p = xb + ((yc * 64 + xc) * 128 + lg * 8) * 2;
            _Float16 m = (_Float16)(valid ? 1.f : 0.f);
#pragma unroll
            for (int kg = 0; kg < 4; ++kg)
                dst[kg] = *(const f16x8*)(p + kg * 64) * m;
        };
        loadA(0, A[0]);
#pragma unroll
        for (int kk = 0; kk < 9; ++kk) {
            if (kk < 8) loadA(kk + 1, A[(kk + 1) & 1]);
            const _Float16* wo = woffT + (kk * 32 + n2 * 16 + lr) * 128 + lg * 8;
#pragma unroll
            for (int kg = 0; kg < 4; ++kg)
                oacc = __builtin_amdgcn_mfma_f32_16x16x32_f16(
                    A[kk & 1][kg], *(const f16x8*)(wo + kg * 32), oacc, 0, 0, 0);
        }
        int oc = n2 * 16 + lr;                 // D: col = oc, row = pos
        if (oc < 18) {
#pragma unroll
            for (int r = 0; r < 4; ++r)
                s_off[oc][m4 * 16 + lg * 4 + r] = oacc[r];
        }
    }
    __syncthreads();

    // ---- Phase B: bilinear meta for all (kk, pos) ----
    for (int e = t; e < 576; e += 512) {
        int pos = e & 63, kk = e >> 6;
        float dy = s_off[2 * kk][pos], dx = s_off[2 * kk + 1][pos];
        float py = (float)(ho + kk / 3 - 1) + dy;
        float px = (float)(pos + kk % 3 - 1) + dx;
        float y0f = floorf(py), x0f = floorf(px);
        float ly = py - y0f, lx = px - x0f;
        int y0 = (int)y0f, x0 = (int)x0f;
        int y1 = y0 + 1, x1 = x0 + 1;
        float my0 = ((unsigned)y0 < 64u) ? 1.f : 0.f;
        float my1 = ((unsigned)y1 < 64u) ? 1.f : 0.f;
        float mx0 = ((unsigned)x0 < 64u) ? 1.f : 0.f;
        float mx1 = ((unsigned)x1 < 64u) ? 1.f : 0.f;
        int y0c = min(max(y0, 0), 63), y1c = min(max(y1, 0), 63);
        int x0c = min(max(x0, 0), 63), x1c = min(max(x1, 0), 63);
        s_pix[e] = make_int4((y0c * 64 + x0c) * 256, (y0c * 64 + x1c) * 256,
                             (y1c * 64 + x0c) * 256, (y1c * 64 + x1c) * 256);
        s_wt[e] = make_float4((1.f - ly) * (1.f - lx) * my0 * mx0,
                              (1.f - ly) * lx * my0 * mx1,
                              ly * (1.f - lx) * my1 * mx0,
                              ly * lx * my1 * mx1);
    }
    __syncthreads();

    // ---- Main loop ----
    int pg = t >> 5;          // pos group 0..15
    int cq = t & 31;          // c-quad (8B units across 256B row)
    int cb = w * 16;          // wave's cout base
    int coff = cq * 8;
    f32x4 acc[4] = {{0.f,0.f,0.f,0.f},{0.f,0.f,0.f,0.f},{0.f,0.f,0.f,0.f},{0.f,0.f,0.f,0.f}};
    f16x8 W[2][4];            // double-buffered W-frags (static idx after unroll)
    uint2 u[4][4];            // in-flight gathers

    auto issueW = [&](int kk, f16x8* Wd) {
        const _Float16* wr = wT + (kk * 128 + cb + lr) * 128 + lg * 8;
#pragma unroll
        for (int kg = 0; kg < 4; ++kg)
            Wd[kg] = *(const f16x8*)(wr + kg * 32);
    };
    auto issueG = [&](int kk) {
#pragma unroll
        for (int i = 0; i < 4; ++i) {
            int pos = pg + i * 16;
            int4 pix = s_pix[kk * 64 + pos];
            u[i][0] = *(const uint2*)(xb + pix.x + coff);
            u[i][1] = *(const uint2*)(xb + pix.y + coff);
            u[i][2] = *(const uint2*)(xb + pix.z + coff);
            u[i][3] = *(const uint2*)(xb + pix.w + coff);
        }
    };
    auto processW = [&](int kk, int buf) {
        char* tp = (char*)s_tile[buf];
#pragma unroll
        for (int i = 0; i < 4; ++i) {
            int pos = pg + i * 16;
            float4 wt = s_wt[kk * 64 + pos];
            h2 w0 = h2{(_Float16)wt.x, (_Float16)wt.x};
            h2 w1 = h2{(_Float16)wt.y, (_Float16)wt.y};
            h2 w2 = h2{(_Float16)wt.z, (_Float16)wt.z};
            h2 w3 = h2{(_Float16)wt.w, (_Float16)wt.w};
            union { uint2 u2; h2 h[2]; } a0, a1, a2, a3, r;
            a0.u2 = u[i][0]; a1.u2 = u[i][1]; a2.u2 = u[i][2]; a3.u2 = u[i][3];
            r.h[0] = w0 * a0.h[0] + w1 * a1.h[0] + w2 * a2.h[0] + w3 * a3.h[0];
            r.h[1] = w0 * a0.h[1] + w1 * a1.h[1] + w2 * a2.h[1] + w3 * a3.h[1];
            *(uint2*)(tp + pos * 256 + (((cq >> 1) ^ (pos & 7)) << 4) + (cq & 1) * 8) = r.u2;
        }
    };

    // prologue: W(0) + gathers(0) -> tile[0]
    issueW(0, W[0]);
    issueG(0);
    processW(0, 0);           // implicit vmcnt wait here (once)
    __syncthreads();

#pragma unroll
    for (int kk = 0; kk < 9; ++kk) {
        if (kk < 8) {
            issueW(kk + 1, W[(kk + 1) & 1]);   // in flight across MFMA
            issueG(kk + 1);                    // in flight across MFMA
        }
        __builtin_amdgcn_sched_barrier(0);     // keep issues above MFMA
        {
            char* rp = (char*)s_tile[kk & 1];
#pragma unroll
            for (int kg = 0; kg < 4; ++kg) {
                int slot = kg * 4 + lg;
#pragma unroll
                for (int n = 0; n < 4; ++n) {
                    int row = n * 16 + lr;
                    f16x8 Bf = *(const f16x8*)(rp + row * 256 + ((slot ^ (row & 7)) << 4));
                    acc[n] = __builtin_amdgcn_mfma_f32_16x16x32_f16(W[kk & 1][kg], Bf, acc[n], 0, 0, 0);
                }
            }
        }
        __builtin_amdgcn_sched_barrier(0);     // keep blend below MFMA
        if (kk < 8) processW(kk + 1, (kk + 1) & 1);  // vmcnt(0) lands HERE
        __syncthreads();
    }

    // Epilogue: cout = cb + lg*4 + r, pos = n*16 + lr
    float* ob = out + ((size_t)(b * 128 + cb + lg * 4)) * 4096 + ho * 64;
#pragma unroll
    for (int n = 0; n < 4; ++n) {
#pragma unroll
        for (int r = 0; r < 4; ++r)
            ob[r * 4096 + n * 16 + lr] = acc[n][r];
    }
}

// ------------------------------------------------------------------
extern "C" void kernel_launch(void* const* d_in, const int* in_sizes, int n_in,
                              void* d_out, int out_size, void* d_ws, size_t ws_size,
                              hipStream_t stream) {
    const float* x    = (const float*)d_in[0];
    const float* woff = (const float*)d_in[1];
    const float* w    = (const float*)d_in[2];
    float* out = (float*)d_out;

    _Float16* wT    = (_Float16*)d_ws;                     // 294,912 B
    _Float16* woffT = (_Float16*)((char*)d_ws + 294912);   //  73,728 B
    _Float16* xT    = (_Float16*)((char*)d_ws + 368640);   // 8,388,608 B

    prep_weights<<<576, 256, 0, stream>>>(w, woff, wT, woffT);
    transpose_nchw_nhwc<<<512, 256, 0, stream>>>(x, (unsigned*)xT);
    deform_fused<<<512, 512, 0, stream>>>(xT, wT, woffT, out);
}